// Round 1
// baseline (3480.939 us; speedup 1.0000x reference)
//
#include <hip/hip_runtime.h>
#include <hip/hip_bf16.h>
#include <cstddef>

#define MB 25
#define KDIM 136     // 16 x-features + 120 hidden
#define GDIM 480     // 4*H gates
#define HID 120
#define TSTEPS 128
#define NSTOCK 100

// ---------------------------------------------------------------------------
// prep: wbuf[(kb*480 + g)*8 + i] = W[g][kb*8+i]  (k<16 -> W_ih, else W_hh)
//       bias[g] = b_ih[g] + b_hh[g]
// ---------------------------------------------------------------------------
__global__ void prep_kernel(const float* __restrict__ W_ih,
                            const float* __restrict__ W_hh,
                            const float* __restrict__ b_ih,
                            const float* __restrict__ b_hh,
                            float* __restrict__ wbuf,
                            float* __restrict__ bias) {
    int idx = blockIdx.x * blockDim.x + threadIdx.x;
    if (idx < 17 * GDIM * 8) {
        int i  = idx & 7;
        int g  = (idx >> 3) % GDIM;
        int kb = idx / (GDIM * 8);
        int k  = kb * 8 + i;
        float v = (k < 16) ? W_ih[g * 16 + k] : W_hh[g * HID + (k - 16)];
        wbuf[idx] = v;
    }
    if (idx < GDIM) bias[idx] = b_ih[idx] + b_hh[idx];
}

// ---------------------------------------------------------------------------
// lstm: one block per 25 batch rows, 128 steps in-block, outputs s[n]
// ---------------------------------------------------------------------------
__global__ __launch_bounds__(512) void lstm_kernel(
        const float* __restrict__ x,
        const float* __restrict__ wbuf,
        const float* __restrict__ bias,
        const float* __restrict__ w_lin,
        const float* __restrict__ b_lin,
        float* __restrict__ s_out) {
    __shared__ float inbuf[MB][KDIM];    // [b][k]: k<16 = x_t, k>=16 = h
    __shared__ float gbuf[GDIM][MB];     // gate pre-activations

    const int tid = threadIdx.x;
    const int blk = blockIdx.x;
    const int n0  = blk * MB;
    const int bb  = n0 / NSTOCK;
    const int ss  = n0 % NSTOCK;
    const float* xbase = x + ((size_t)bb * TSTEPS * NSTOCK + ss) * 16;

    // zero h-part of inbuf
    for (int idx = tid; idx < MB * HID; idx += 512) {
        int b = idx / HID, j = idx % HID;
        inbuf[b][16 + j] = 0.f;
    }
    // load x_0 (25*16 = 400 contiguous floats)
    if (tid < 100) {
        const float4 v = *(const float4*)(xbase + tid * 4);
        int b = tid >> 2, k = (tid & 3) * 4;
        *(float4*)&inbuf[b][k] = v;
    }

    float c_reg[MB];
#pragma unroll
    for (int b = 0; b < MB; ++b) c_reg[b] = 0.f;
    float bia = (tid < GDIM) ? bias[tid] : 0.f;

    for (int t = 0; t < TSTEPS; ++t) {
        __syncthreads();   // inbuf (x_t, h_{t-1}) ready
        if (tid < GDIM) {
            float acc[MB];
#pragma unroll
            for (int b = 0; b < MB; ++b) acc[b] = 0.f;
            const float* wp = wbuf + (size_t)tid * 8;
            for (int kb = 0; kb < 17; ++kb) {
                const float4 w0 = *(const float4*)(wp + (size_t)kb * GDIM * 8);
                const float4 w1 = *(const float4*)(wp + (size_t)kb * GDIM * 8 + 4);
#pragma unroll
                for (int b = 0; b < MB; ++b) {
                    const float4 v0 = *(const float4*)&inbuf[b][kb * 8];
                    const float4 v1 = *(const float4*)&inbuf[b][kb * 8 + 4];
                    acc[b] += w0.x * v0.x + w0.y * v0.y + w0.z * v0.z + w0.w * v0.w
                            + w1.x * v1.x + w1.y * v1.y + w1.z * v1.z + w1.w * v1.w;
                }
            }
#pragma unroll
            for (int b = 0; b < MB; ++b) gbuf[tid][b] = acc[b] + bia;
        }
        __syncthreads();   // gbuf ready; everyone done reading inbuf
        if (tid < HID) {
#pragma unroll 5
            for (int b = 0; b < MB; ++b) {
                float gi = gbuf[tid][b];
                float gf = gbuf[HID + tid][b];
                float gg = gbuf[2 * HID + tid][b];
                float go = gbuf[3 * HID + tid][b];
                gi = 1.f / (1.f + __expf(-gi));
                gf = 1.f / (1.f + __expf(-gf));
                gg = 1.f - 2.f / (1.f + __expf(2.f * gg));   // tanh, NaN-safe
                go = 1.f / (1.f + __expf(-go));
                float c = gf * c_reg[b] + gi * gg;
                c_reg[b] = c;
                float h = go * (1.f - 2.f / (1.f + __expf(2.f * c)));
                inbuf[b][16 + tid] = h;
            }
        }
        // prefetch x_{t+1}
        if (t < TSTEPS - 1 && tid >= 384 && tid < 484) {
            int ti = tid - 384;
            const float4 v = *(const float4*)(xbase + (size_t)(t + 1) * (NSTOCK * 16) + ti * 4);
            int b = ti >> 2, k = (ti & 3) * 4;
            *(float4*)&inbuf[b][k] = v;
        }
    }
    __syncthreads();
    // s[n] = h_last . w_lin + b_lin
    if (tid < MB) {
        float acc = b_lin[0];
        for (int j = 0; j < HID; ++j) acc += inbuf[tid][16 + j] * w_lin[j];
        s_out[n0 + tid] = acc;
    }
}

// ---------------------------------------------------------------------------
// phat: per batch b, NeuralSort relaxed perm matrix -> fooT[m][b] (transposed)
// p_hat[b,i,j] = softmax_j( (s[b,j]*(99-2i) - rowsum[b,j]) / 5 )
// ---------------------------------------------------------------------------
__global__ __launch_bounds__(128) void phat_kernel(const float* __restrict__ s,
                                                   float* __restrict__ fooT) {
    __shared__ float a[NSTOCK], c[NSTOCK];
    const int b = blockIdx.x, tid = threadIdx.x;
    const float* sb = s + b * NSTOCK;
    if (tid < NSTOCK) {
        float sj = sb[tid];
        float rs = 0.f;
        for (int i2 = 0; i2 < NSTOCK; ++i2) rs += fabsf(sj - sb[i2]);
        a[tid] = sj * 0.2f;   // s/tau
        c[tid] = rs * 0.2f;   // rowsum/tau
    }
    __syncthreads();
    if (tid < NSTOCK) {
        const int i = tid;
        const float sci = (float)(99 - 2 * i);
        float m = -1e30f;
        for (int j = 0; j < NSTOCK; ++j) m = fmaxf(m, sci * a[j] - c[j]);
        float sum = 0.f;
        for (int j = 0; j < NSTOCK; ++j) sum += __expf(sci * a[j] - c[j] - m);
        const float inv = 1.f / sum;
        for (int j = 0; j < NSTOCK; ++j)
            fooT[(size_t)(i * NSTOCK + j) * 64 + b] = __expf(sci * a[j] - c[j] - m) * inv;
    }
}

// ---------------------------------------------------------------------------
// mlp1: z2T[u][b] = relu( sum_m fooT[m][b] * W2[u][m] + b2[u] )
// wave-per-u, lane = b (coalesced fooT reads, scalar W2 reads)
// ---------------------------------------------------------------------------
__global__ __launch_bounds__(256) void mlp1_kernel(const float* __restrict__ fooT,
                                                   const float* __restrict__ W2,
                                                   const float* __restrict__ b2,
                                                   float* __restrict__ z2T) {
    const int tid  = threadIdx.x;
    const int u    = blockIdx.x * 4 + (tid >> 6);
    const int lane = tid & 63;
    const float* wrow = W2 + (size_t)u * 10000;
    float acc = 0.f;
    for (int m = 0; m < 10000; m += 8) {
#pragma unroll
        for (int q = 0; q < 8; ++q)
            acc += fooT[(size_t)(m + q) * 64 + lane] * wrow[m + q];
    }
    z2T[u * 64 + lane] = fmaxf(acc + b2[u], 0.f);
}

// ---------------------------------------------------------------------------
// mlp2: z3[b][v] = sum_u z2[b][u]*W3[v][u] + b3[v]; out = softmax_v
// ---------------------------------------------------------------------------
__global__ __launch_bounds__(128) void mlp2_kernel(const float* __restrict__ z2T,
                                                   const float* __restrict__ W3,
                                                   const float* __restrict__ b3,
                                                   float* __restrict__ out) {
    __shared__ float zs[256];
    __shared__ float logits[NSTOCK];
    const int b = blockIdx.x, tid = threadIdx.x;
    for (int u = tid; u < 256; u += 128) zs[u] = z2T[u * 64 + b];
    __syncthreads();
    if (tid < NSTOCK) {
        float acc = b3[tid];
        const float* w = W3 + tid * 256;
        for (int u = 0; u < 256; ++u) acc += zs[u] * w[u];
        logits[tid] = acc;
    }
    __syncthreads();
    if (tid < NSTOCK) {
        float m = -1e30f;
        for (int j = 0; j < NSTOCK; ++j) m = fmaxf(m, logits[j]);
        float sum = 0.f;
        for (int j = 0; j < NSTOCK; ++j) sum += __expf(logits[j] - m);
        out[b * NSTOCK + tid] = __expf(logits[tid] - m) / sum;
    }
}

// ---------------------------------------------------------------------------
extern "C" void kernel_launch(void* const* d_in, const int* in_sizes, int n_in,
                              void* d_out, int out_size, void* d_ws, size_t ws_size,
                              hipStream_t stream) {
    const float* x     = (const float*)d_in[0];
    const float* W_ih  = (const float*)d_in[1];
    const float* W_hh  = (const float*)d_in[2];
    const float* b_ih  = (const float*)d_in[3];
    const float* b_hh  = (const float*)d_in[4];
    const float* w_lin = (const float*)d_in[5];
    const float* b_lin = (const float*)d_in[6];
    const float* W2    = (const float*)d_in[7];
    const float* b2    = (const float*)d_in[8];
    const float* W3    = (const float*)d_in[9];
    const float* b3    = (const float*)d_in[10];

    float* ws   = (float*)d_ws;
    float* wbuf = ws;                 // 17*480*8 = 65280
    float* bias = ws + 65280;         // 480
    float* sbuf = ws + 65760;         // 6400
    float* fooT = ws + 72160;         // 10000*64 = 640000
    float* z2T  = ws + 712160;        // 256*64 = 16384
    float* out  = (float*)d_out;

    prep_kernel<<<(17 * GDIM * 8 + 255) / 256, 256, 0, stream>>>(W_ih, W_hh, b_ih, b_hh, wbuf, bias);
    lstm_kernel<<<256, 512, 0, stream>>>(x, wbuf, bias, w_lin, b_lin, sbuf);
    phat_kernel<<<64, 128, 0, stream>>>(sbuf, fooT);
    mlp1_kernel<<<64, 256, 0, stream>>>(fooT, W2, b2, z2T);
    mlp2_kernel<<<64, 128, 0, stream>>>(z2T, W3, b3, out);
}

// Round 3
// 793.995 us; speedup vs baseline: 4.3841x; 4.3841x over previous
//
#include <hip/hip_runtime.h>
#include <hip/hip_bf16.h>
#include <cstddef>

#define NSTOCK 100
#define LOG2E 1.4426950408889634f

typedef _Float16 f16x8 __attribute__((ext_vector_type(8)));
typedef float f32x16 __attribute__((ext_vector_type(16)));

static __device__ __forceinline__ float rcpf(float x){ return __builtin_amdgcn_rcpf(x); }
static __device__ __forceinline__ float exp2f_(float x){ return __builtin_amdgcn_exp2f(x); }

// ---------------------------------------------------------------------------
// prep: build permuted+scaled weight matrix Wp[512][144] and biasp[512].
// perm slot p = w*64 + nt*32 + q  (w=wave, nt=tile, q=lane&31):
//   type = nt*2 + (q>>4)  (0=i,1=f,2=g,3=o),  j = w*16 + (q&15)
//   orig gate = type*120 + j   (pad if j>=120)
// k: 0..15 = x features (W_ih), 16..135 = h (W_hh), 136..143 pad.
// rows pre-scaled by log2e (sigmoid) / 2*log2e (tanh g-row).
// ---------------------------------------------------------------------------
__global__ void prep_kernel(const float* __restrict__ W_ih,
                            const float* __restrict__ W_hh,
                            const float* __restrict__ b_ih,
                            const float* __restrict__ b_hh,
                            float* __restrict__ Wp,
                            float* __restrict__ biasp) {
    int idx = blockIdx.x * 256 + threadIdx.x;
    if (idx < 512 * 144) {
        int k = idx % 144;
        int p = idx / 144;
        int w = p >> 6, r = p & 63, nt = r >> 5, q = r & 31;
        int type = nt * 2 + (q >> 4);
        int j = w * 16 + (q & 15);
        float v = 0.f;
        if (j < 120 && k < 136) {
            int g = type * 120 + j;
            v = (k < 16) ? W_ih[g * 16 + k] : W_hh[g * 120 + (k - 16)];
            v *= (type == 2) ? 2.f * LOG2E : LOG2E;
        }
        Wp[idx] = v;
    }
    if (idx < 512) {
        int p = idx;
        int w = p >> 6, r = p & 63, nt = r >> 5, q = r & 31;
        int type = nt * 2 + (q >> 4);
        int j = w * 16 + (q & 15);
        float v = 0.f;
        if (j < 120) {
            int g = type * 120 + j;
            v = (b_ih[g] + b_hh[g]) * ((type == 2) ? 2.f * LOG2E : LOG2E);
        }
        biasp[idx] = v;
    }
}

// ---------------------------------------------------------------------------
// lstm: 200 blocks x 512 thr, 32 batch rows/block, 128 steps in-block.
// Weights persistent in registers (fp16 split hi/lo), A-operand (x|h) staged
// in double-buffered LDS fragment layout, activations in-register via
// shfl_xor(16) pair exchange. fp32-equivalent via 3-term fp16-split MFMA.
// ---------------------------------------------------------------------------
__global__ __launch_bounds__(512) void lstm_kernel(
        const float* __restrict__ x,
        const float* __restrict__ Wp,
        const float* __restrict__ biasp,
        const float* __restrict__ w_lin,
        const float* __restrict__ b_lin,
        float* __restrict__ s_out) {
    __shared__ __align__(16) _Float16 fragHi[2][9][64][8];
    __shared__ __align__(16) _Float16 fragLo[2][9][64][8];
    __shared__ float sred[15][32];

    const int tid   = threadIdx.x;
    const int lane  = tid & 63;
    const int w     = tid >> 6;        // wave 0..7
    const int l31   = lane & 31;
    const int lhalf = lane >> 5;
    const int n0    = blockIdx.x * 32;

    // ---- persistent weight fragments ----
    f16x8 bh[2][9], bl[2][9];
#pragma unroll
    for (int nt = 0; nt < 2; ++nt) {
        const int p = w * 64 + nt * 32 + l31;
#pragma unroll
        for (int kt = 0; kt < 9; ++kt) {
            const float* wp = Wp + p * 144 + kt * 16 + lhalf * 8;
            f16x8 hi, lo;
#pragma unroll
            for (int e = 0; e < 8; ++e) {
                float v = wp[e];
                _Float16 h_ = (_Float16)v;
                hi[e] = h_;
                lo[e] = (_Float16)(v - (float)h_);
            }
            bh[nt][kt] = hi; bl[nt][kt] = lo;
        }
    }
    const float bias0 = biasp[w * 64 + l31];
    const float bias1 = biasp[w * 64 + 32 + l31];

    // ---- zero h-region (kt 1..8) of both buffers ----
    {
        f16x8 z;
#pragma unroll
        for (int e = 0; e < 8; ++e) z[e] = (_Float16)0.f;
        for (int ii = tid; ii < 2 * 8 * 64; ii += 512) {
            int bf = ii >> 9, kt = 1 + ((ii >> 6) & 7), ln = ii & 63;
            *(f16x8*)&fragHi[bf][kt][ln][0] = z;
            *(f16x8*)&fragLo[bf][kt][ln][0] = z;
        }
    }

    // ---- x staging (wave 0): thread -> (batch bx, half halfx) ----
    const int bx = lane >> 1;
    const int halfx = lane & 1;
    const int nx = n0 + bx;
    const int bbx = nx / NSTOCK, ssx = nx % NSTOCK;
    const float* xbase = x + (size_t)bbx * 204800 + ssx * 16 + halfx * 8;
    if (w == 0) {   // stage x_0 into buf 0
        float4 v0 = *(const float4*)(xbase);
        float4 v1 = *(const float4*)(xbase + 4);
        float vv[8] = {v0.x, v0.y, v0.z, v0.w, v1.x, v1.y, v1.z, v1.w};
        f16x8 hi, lo;
#pragma unroll
        for (int e = 0; e < 8; ++e) {
            _Float16 h_ = (_Float16)vv[e];
            hi[e] = h_; lo[e] = (_Float16)(vv[e] - (float)h_);
        }
        *(f16x8*)&fragHi[0][0][bx + 32 * halfx][0] = hi;
        *(f16x8*)&fragLo[0][0][bx + 32 * halfx][0] = lo;
    }
    __syncthreads();

    // activation lane constants
    const int jj  = lane & 15;            // j within wave: j = w*16 + jj
    const int sel = (lane >> 4) & 1;      // 0: holds i(g), 1: holds f(o)
    const bool actv = (w * 16 + jj) < 120;
    const int ktw = 1 + w;                // frag kt this wave writes
    const int wlane = (jj >> 3);          // frag lane-half from jj
    const int welem = jj & 7;

    float creg[8];
#pragma unroll
    for (int e = 0; e < 8; ++e) creg[e] = 0.f;

    for (int t = 0; t < 128; ++t) {
        const int rb = t & 1;
        const int wb = rb ^ 1;
        // prefetch x_{t+1} (wave 0) — latency hidden under GEMM
        float4 xv0, xv1;
        if (w == 0) {
            int tt = (t < 127) ? t + 1 : 127;
            const float* xp = xbase + (size_t)tt * 1600;
            xv0 = *(const float4*)xp;
            xv1 = *(const float4*)(xp + 4);
        }
        // ---- GEMM: preacts = [x|h] @ Wp^T + bias (split-fp16, fp32 acc) ----
        f32x16 acc0, acc1;
#pragma unroll
        for (int r = 0; r < 16; ++r) { acc0[r] = bias0; acc1[r] = bias1; }
#pragma unroll
        for (int kt = 0; kt < 9; ++kt) {
            f16x8 ah = *(const f16x8*)&fragHi[rb][kt][lane][0];
            f16x8 al = *(const f16x8*)&fragLo[rb][kt][lane][0];
            acc0 = __builtin_amdgcn_mfma_f32_32x32x16_f16(ah, bh[0][kt], acc0, 0, 0, 0);
            acc1 = __builtin_amdgcn_mfma_f32_32x32x16_f16(ah, bh[1][kt], acc1, 0, 0, 0);
            acc0 = __builtin_amdgcn_mfma_f32_32x32x16_f16(ah, bl[0][kt], acc0, 0, 0, 0);
            acc1 = __builtin_amdgcn_mfma_f32_32x32x16_f16(ah, bl[1][kt], acc1, 0, 0, 0);
            acc0 = __builtin_amdgcn_mfma_f32_32x32x16_f16(al, bh[0][kt], acc0, 0, 0, 0);
            acc1 = __builtin_amdgcn_mfma_f32_32x32x16_f16(al, bh[1][kt], acc1, 0, 0, 0);
        }
        // ---- activation, in-register; lane pair (m, m+16) swaps i/f and g/o
        // lane sel=0 computes batch rows r_eff=rr, sel=1 rows r_eff=rr+8.
#pragma unroll
        for (int rr = 0; rr < 8; ++rr) {
            float send0 = sel ? acc0[rr] : acc0[rr + 8];
            float send1 = sel ? acc1[rr] : acc1[rr + 8];
            float recv0 = __shfl_xor(send0, 16);
            float recv1 = __shfl_xor(send1, 16);
            float own0 = sel ? acc0[rr + 8] : acc0[rr];
            float own1 = sel ? acc1[rr + 8] : acc1[rr];
            float iv = sel ? recv0 : own0;
            float fv = sel ? own0 : recv0;
            float gv = sel ? recv1 : own1;
            float ov = sel ? own1 : recv1;
            // preacts pre-scaled by log2e (2*log2e for g)
            float si = rcpf(1.f + exp2f_(-iv));
            float sf = rcpf(1.f + exp2f_(-fv));
            float tg = 1.f - 2.f * rcpf(1.f + exp2f_(gv));
            float so = rcpf(1.f + exp2f_(-ov));
            float c = sf * creg[rr] + si * tg;
            creg[rr] = c;
            float h = so * (1.f - 2.f * rcpf(1.f + exp2f_(c * 2.8853900817779268f)));
            if (actv) {
                _Float16 hh = (_Float16)h;
                _Float16 hl = (_Float16)(h - (float)hh);
                int b_row = (rr & 3) + 8 * (rr >> 2) + 16 * sel + 4 * lhalf;
                fragHi[wb][ktw][b_row + 32 * wlane][welem] = hh;
                fragLo[wb][ktw][b_row + 32 * wlane][welem] = hl;
            }
        }
        // ---- stage x_{t+1} into write buffer (wave 0) ----
        if (w == 0) {
            float vv[8] = {xv0.x, xv0.y, xv0.z, xv0.w, xv1.x, xv1.y, xv1.z, xv1.w};
            f16x8 hi, lo;
#pragma unroll
            for (int e = 0; e < 8; ++e) {
                _Float16 h_ = (_Float16)vv[e];
                hi[e] = h_; lo[e] = (_Float16)(vv[e] - (float)h_);
            }
            *(f16x8*)&fragHi[wb][0][bx + 32 * halfx][0] = hi;
            *(f16x8*)&fragLo[wb][0][bx + 32 * halfx][0] = lo;
        }
        __syncthreads();
    }

    // ---- s = h_last . w_lin + b_lin  (final h is in buffer 0) ----
    if (tid < 480) {
        const int b = tid & 31;
        const int jg = tid >> 5;                 // 0..14, j = jg*8+e
        const int lane_ = b + 32 * (jg & 1);
        const int ktE = 1 + (jg >> 1);
        f16x8 hi = *(const f16x8*)&fragHi[0][ktE][lane_][0];
        f16x8 lo = *(const f16x8*)&fragLo[0][ktE][lane_][0];
        float sp = 0.f;
#pragma unroll
        for (int e = 0; e < 8; ++e)
            sp += ((float)hi[e] + (float)lo[e]) * w_lin[jg * 8 + e];
        sred[jg][b] = sp;
    }
    __syncthreads();
    if (tid < 32) {
        float s = b_lin[0];
#pragma unroll
        for (int jg2 = 0; jg2 < 15; ++jg2) s += sred[jg2][tid];
        s_out[n0 + tid] = s;
    }
}

// ---------------------------------------------------------------------------
// phat: per batch b, NeuralSort relaxed perm matrix -> fooT[m][b] (transposed)
// ---------------------------------------------------------------------------
__global__ __launch_bounds__(128) void phat_kernel(const float* __restrict__ s,
                                                   float* __restrict__ fooT) {
    __shared__ float a[NSTOCK], c[NSTOCK];
    const int b = blockIdx.x, tid = threadIdx.x;
    const float* sb = s + b * NSTOCK;
    if (tid < NSTOCK) {
        float sj = sb[tid];
        float rs = 0.f;
        for (int i2 = 0; i2 < NSTOCK; ++i2) rs += fabsf(sj - sb[i2]);
        a[tid] = sj * 0.2f;
        c[tid] = rs * 0.2f;
    }
    __syncthreads();
    if (tid < NSTOCK) {
        const int i = tid;
        const float sci = (float)(99 - 2 * i);
        float m = -1e30f;
        for (int j = 0; j < NSTOCK; ++j) m = fmaxf(m, sci * a[j] - c[j]);
        float sum = 0.f;
        for (int j = 0; j < NSTOCK; ++j) sum += __expf(sci * a[j] - c[j] - m);
        const float inv = 1.f / sum;
        for (int j = 0; j < NSTOCK; ++j)
            fooT[(size_t)(i * NSTOCK + j) * 64 + b] = __expf(sci * a[j] - c[j] - m) * inv;
    }
}

// ---------------------------------------------------------------------------
// mlp1: z2T[u][b] = relu(sum_m fooT[m][b]*W2[u][m] + b2[u])
// 4 u per block, 8 waves each over a 1250-m chunk, LDS cross-wave reduce.
// ---------------------------------------------------------------------------
__global__ __launch_bounds__(512) void mlp1_kernel(const float* __restrict__ fooT,
                                                   const float* __restrict__ W2,
                                                   const float* __restrict__ b2,
                                                   float* __restrict__ z2T) {
    __shared__ float part[8][4][64];
    const int tid = threadIdx.x;
    const int wv = tid >> 6, lane = tid & 63;
    const int u0 = blockIdx.x * 4;
    const int m0 = wv * 1250;
    float a0 = 0.f, a1 = 0.f, a2 = 0.f, a3 = 0.f;
    for (int mi = 0; mi < 1250; ++mi) {
        int m = m0 + mi;
        float v = fooT[(size_t)m * 64 + lane];
        a0 += v * W2[(size_t)(u0 + 0) * 10000 + m];
        a1 += v * W2[(size_t)(u0 + 1) * 10000 + m];
        a2 += v * W2[(size_t)(u0 + 2) * 10000 + m];
        a3 += v * W2[(size_t)(u0 + 3) * 10000 + m];
    }
    part[wv][0][lane] = a0; part[wv][1][lane] = a1;
    part[wv][2][lane] = a2; part[wv][3][lane] = a3;
    __syncthreads();
    if (tid < 256) {
        int q = tid >> 6, b = tid & 63;
        float s = b2[u0 + q];
#pragma unroll
        for (int w2 = 0; w2 < 8; ++w2) s += part[w2][q][b];
        z2T[(u0 + q) * 64 + b] = fmaxf(s, 0.f);
    }
}

// ---------------------------------------------------------------------------
// mlp2: z3[b][v] = sum_u z2[b][u]*W3[v][u] + b3[v]; out = softmax_v
// ---------------------------------------------------------------------------
__global__ __launch_bounds__(128) void mlp2_kernel(const float* __restrict__ z2T,
                                                   const float* __restrict__ W3,
                                                   const float* __restrict__ b3,
                                                   float* __restrict__ out) {
    __shared__ float zs[256];
    __shared__ float logits[NSTOCK];
    const int b = blockIdx.x, tid = threadIdx.x;
    for (int u = tid; u < 256; u += 128) zs[u] = z2T[u * 64 + b];
    __syncthreads();
    if (tid < NSTOCK) {
        float acc = b3[tid];
        const float* wr = W3 + tid * 256;
        for (int u = 0; u < 256; ++u) acc += zs[u] * wr[u];
        logits[tid] = acc;
    }
    __syncthreads();
    if (tid < NSTOCK) {
        float m = -1e30f;
        for (int j = 0; j < NSTOCK; ++j) m = fmaxf(m, logits[j]);
        float sum = 0.f;
        for (int j = 0; j < NSTOCK; ++j) sum += __expf(logits[j] - m);
        out[b * NSTOCK + tid] = __expf(logits[tid] - m) / sum;
    }
}

// ---------------------------------------------------------------------------
extern "C" void kernel_launch(void* const* d_in, const int* in_sizes, int n_in,
                              void* d_out, int out_size, void* d_ws, size_t ws_size,
                              hipStream_t stream) {
    const float* x     = (const float*)d_in[0];
    const float* W_ih  = (const float*)d_in[1];
    const float* W_hh  = (const float*)d_in[2];
    const float* b_ih  = (const float*)d_in[3];
    const float* b_hh  = (const float*)d_in[4];
    const float* w_lin = (const float*)d_in[5];
    const float* b_lin = (const float*)d_in[6];
    const float* W2    = (const float*)d_in[7];
    const float* b2    = (const float*)d_in[8];
    const float* W3    = (const float*)d_in[9];
    const float* b3    = (const float*)d_in[10];

    float* ws    = (float*)d_ws;
    float* Wp    = ws;                 // 512*144 = 73728
    float* biasp = ws + 73728;         // 512
    float* sbuf  = ws + 74240;         // 6400
    float* fooT  = ws + 80640;         // 10000*64 = 640000
    float* z2T   = ws + 720640;        // 256*64 = 16384
    float* out   = (float*)d_out;

    prep_kernel<<<288, 256, 0, stream>>>(W_ih, W_hh, b_ih, b_hh, Wp, biasp);
    lstm_kernel<<<200, 512, 0, stream>>>(x, Wp, biasp, w_lin, b_lin, sbuf);
    phat_kernel<<<64, 128, 0, stream>>>(sbuf, fooT);
    mlp1_kernel<<<64, 512, 0, stream>>>(fooT, W2, b2, z2T);
    mlp2_kernel<<<64, 128, 0, stream>>>(z2T, W3, b3, out);
}